// Round 7
// baseline (339.411 us; speedup 1.0000x reference)
//
#include <hip/hip_runtime.h>

typedef unsigned long long u64;
typedef float f32x4 __attribute__((ext_vector_type(4)));

#define H_SZ 4096
#define NBITS 16
#define NFEAT 128
#define NCLS 10
#define THETA 8

// Bit-packing convention: for a chunk c of 256 positions, act word (c,j),
// j=0..3, has bit i <-> position p = c*256 + 4*i + j. This is exactly what
// per-component ballots of a lane-major float4 load produce.
// Encode check: i=4k+m -> p = c*256+16k+4m+j -> feature f = c*16+k,
// threshold t = 4m+j, thr = (t+1)/(NBITS+1) — matches the reference.

// ---------------------------------------------------------------------------
// 64x64 bit-matrix transpose across the 64 lanes (6 butterfly stages).
// In: lane l holds row l (bit b = M[l][b]). Out: lane l holds column l.
// ---------------------------------------------------------------------------
__device__ __forceinline__ u64 bfly_stage(u64 x, int lane, int d, u64 Md) {
    u64 p = __shfl_xor(x, d);
    return (lane & d) ? ((x & Md) | ((p >> d) & ~Md))
                      : ((x & ~Md) | ((p << d) & Md));
}

__device__ __forceinline__ u64 transpose64(u64 x, int lane) {
    x = bfly_stage(x, lane, 32, 0xFFFFFFFF00000000ULL);
    x = bfly_stage(x, lane, 16, 0xFFFF0000FFFF0000ULL);
    x = bfly_stage(x, lane,  8, 0xFF00FF00FF00FF00ULL);
    x = bfly_stage(x, lane,  4, 0xF0F0F0F0F0F0F0F0ULL);
    x = bfly_stage(x, lane,  2, 0xCCCCCCCCCCCCCCCCULL);
    x = bfly_stage(x, lane,  1, 0xAAAAAAAAAAAAAAAAULL);
    return x;
}

// ---------------------------------------------------------------------------
// Layer: wave = ONE (h,s) row. 8192 waves = 1024 blocks x 512 thr = exactly
// 4 blocks/CU x 8 waves = 32 waves/CU (launch_bounds(512,8), VGPR <= 64 —
// R6 compiled at 64 with this inner loop). Lane = batch: act words from LDS,
// wave-uniform sign masks via ballot. Segment pair combines through LDS.
//  - !FROM_FIRED (layer 0): encode fused — thread (c=tid>>6, b=tid&63)
//    builds act words (c, j=0..3, b) directly into LDS from x row b
//    (16 scalar L2-broadcast loads, inline-const thresholds, ~0.25us head
//    hidden under the peeled W0 loads). Block 0 also zeroes out[].
//  - FROM_FIRED (layers 1/2): staging = in-block 64x64 butterfly transpose
//    of prev fired[] (64 (c,j) pairs, 8 per warp), hidden under peel.
// ---------------------------------------------------------------------------
template <int P, bool FROM_FIRED>
__global__ __launch_bounds__(512, 8) void layer_kernel(
    const float* __restrict__ W, const u64* __restrict__ actin,
    u64* __restrict__ fired_out, const float* __restrict__ x,
    float* __restrict__ out, int out_n)
{
    constexpr int NC = P / 256;              // chunks per row
    constexpr int NW = P / 64;               // act words
    __shared__ __align__(16) u64 lds[NW * 64];   // 16 KB (P=2048) / 32 KB (4096)
    __shared__ u64 bal[8];
    int tid = threadIdx.x;
    int lane = tid & 63;
    int warp = tid >> 6;                     // 0..7
    int row = blockIdx.x * 8 + warp;         // (h,s) id, 0..8191
    const f32x4* wr = (const f32x4*)(W + (size_t)row * P) + lane;

    // peel: first 4 chunks in flight during staging
    f32x4 pw[4];
    #pragma unroll
    for (int c = 0; c < 4; c++) pw[c] = __builtin_nontemporal_load(wr + c * 64);

    if constexpr (!FROM_FIRED) {
        if (blockIdx.x == 0)                  // zero out[] before output kernel
            for (int i = tid; i < out_n; i += 512) out[i] = 0.0f;
        // Encode: thread (c, b) builds words (c, j=0..3, b) into LDS.
        int c = tid >> 6, b = tid & 63;       // c=0..7, b=0..63
        const float* xb = x + b * NFEAT + c * 16;
        u64 wj0 = 0, wj1 = 0, wj2 = 0, wj3 = 0;
        #pragma unroll
        for (int k = 0; k < 16; k++) {
            float xv = xb[k];
            #pragma unroll
            for (int m = 0; m < 4; m++) {
                // thr = (t+1)/(NBITS+1), t = 4m+j — identical fp32 math to ref
                wj0 |= (u64)(xv >= (float)(4 * m + 1) / (NBITS + 1.0f)) << (4 * k + m);
                wj1 |= (u64)(xv >= (float)(4 * m + 2) / (NBITS + 1.0f)) << (4 * k + m);
                wj2 |= (u64)(xv >= (float)(4 * m + 3) / (NBITS + 1.0f)) << (4 * k + m);
                wj3 |= (u64)(xv >= (float)(4 * m + 4) / (NBITS + 1.0f)) << (4 * k + m);
            }
        }
        lds[(c * 4 + 0) * 64 + b] = wj0;
        lds[(c * 4 + 1) * 64 + b] = wj1;
        lds[(c * 4 + 2) * 64 + b] = wj2;
        lds[(c * 4 + 3) * 64 + b] = wj3;
    } else {
        // 64 (c,j) pairs; warp takes idx = warp*8 + k:
        // word (c,j) bit i = fired[c*256 + 4i + j] bit b  (proven in R2)
        #pragma unroll
        for (int k = 0; k < 8; k++) {
            int idx = warp * 8 + k;
            u64 xw = actin[(idx >> 2) * 256 + 4 * lane + (idx & 3)];
            xw = transpose64(xw, lane);
            lds[idx * 64 + lane] = xw;
        }
    }
    __syncthreads();

    unsigned zp = 0, zn = 0;
    auto body = [&](int c, f32x4 a) {
        const u64* p = lds + c * 256 + lane;
        u64 A0 = p[0], A1 = p[64], A2 = p[128], A3 = p[192];
        u64 m;
        m = __ballot(a.x > 0.0f); zp += __builtin_popcountll(A0 & m);
        m = __ballot(a.x < 0.0f); zn += __builtin_popcountll(A0 & m);
        m = __ballot(a.y > 0.0f); zp += __builtin_popcountll(A1 & m);
        m = __ballot(a.y < 0.0f); zn += __builtin_popcountll(A1 & m);
        m = __ballot(a.z > 0.0f); zp += __builtin_popcountll(A2 & m);
        m = __ballot(a.z < 0.0f); zn += __builtin_popcountll(A2 & m);
        m = __ballot(a.w > 0.0f); zp += __builtin_popcountll(A3 & m);
        m = __ballot(a.w < 0.0f); zn += __builtin_popcountll(A3 & m);
    };
    #pragma unroll
    for (int c = 0; c < 4; c++) body(c, pw[c]);
    #pragma unroll 4
    for (int c = 4; c < NC; c++)
        body(c, __builtin_nontemporal_load(wr + c * 64));

    int z = (int)zp - (int)zn;
    u64 bz = __ballot(z >= THETA);
    if (lane == 0) bal[warp] = bz;
    __syncthreads();
    // h = blockIdx*4 + t sources rows 8*blockIdx + 2t (s=0) and +1 (s=1)
    if (tid < 4) fired_out[blockIdx.x * 4 + tid] = bal[2 * tid] | bal[2 * tid + 1];
}

// ---------------------------------------------------------------------------
// Output: out[b,c] = sum_l sum_h fired_l[b,h] * outW[l,h,c]; lane = batch.
// Block-uniform (l,c); 4 wave-partials reduce in LDS -> 1 atomic per
// (block, lane). grid: 480 blocks x 256 thr (3 x 10 x 64 chunks of 64 h).
// ---------------------------------------------------------------------------
__global__ void output_kernel(const float* __restrict__ outW,
                              const u64* __restrict__ fired,
                              float* __restrict__ out) {
    __shared__ float red[4][64];
    int tid = threadIdx.x;
    int lane = tid & 63;
    int warp = tid >> 6;
    int wid = blockIdx.x * 4 + warp;   // 0..1919
    int l = wid / (NCLS * 64);
    int rem = wid % (NCLS * 64);
    int c = rem / 64;
    int chunk = rem % 64;
    const u64* fl = fired + l * H_SZ;
    int h0 = chunk * 64;
    float acc = 0.0f;
    #pragma unroll 8
    for (int h = h0; h < h0 + 64; h++) {
        float wv = outW[((size_t)(l * H_SZ + h)) * NCLS + c];
        if ((fl[h] >> lane) & 1ULL) acc += wv;
    }
    red[warp][lane] = acc;
    __syncthreads();
    if (warp == 0) {
        float s = red[0][lane] + red[1][lane] + red[2][lane] + red[3][lane];
        atomicAdd(&out[lane * NCLS + c], s);
    }
}

// ---------------------------------------------------------------------------
extern "C" void kernel_launch(void* const* d_in, const int* in_sizes, int n_in,
                              void* d_out, int out_size, void* d_ws, size_t ws_size,
                              hipStream_t stream) {
    const float* x    = (const float*)d_in[0];
    const float* W0   = (const float*)d_in[1];
    const float* W1   = (const float*)d_in[2];
    const float* W2   = (const float*)d_in[3];
    const float* outW = (const float*)d_in[4];
    float* out = (float*)d_out;

    u64* fired = (u64*)d_ws;                 // 3*4096 u64 = 96 KB

    layer_kernel<2048, false><<<1024, 512, 0, stream>>>(W0, nullptr, fired,
                                                        x, out, out_size);
    layer_kernel<4096, true ><<<1024, 512, 0, stream>>>(W1, fired, fired + H_SZ,
                                                        nullptr, nullptr, 0);
    layer_kernel<4096, true ><<<1024, 512, 0, stream>>>(W2, fired + H_SZ, fired + 2 * H_SZ,
                                                        nullptr, nullptr, 0);
    output_kernel<<<480, 256, 0, stream>>>(outW, fired, out);
}

// Round 8
// 332.642 us; speedup vs baseline: 1.0203x; 1.0203x over previous
//
#include <hip/hip_runtime.h>

typedef unsigned long long u64;
typedef float f32x4 __attribute__((ext_vector_type(4)));

#define H_SZ 4096
#define NBITS 16
#define NFEAT 128
#define NCLS 10
#define THETA 8

// Bit-packing convention: for a chunk c of 256 positions, act word (c,j),
// j=0..3, has bit i <-> position p = c*256 + 4*i + j. This is exactly what
// per-component ballots of a lane-major float4 load produce.

// ---------------------------------------------------------------------------
// Encode: x[64,128] -> thermometer bits packed per convention.
// actp0[(c*4+j)*64 + b], c=0..7 (P0=2048, 32 words).
// Block 0 also zeroes out[] (stream order puts this before output_kernel).
// NOTE: kept as a standalone ~1us dispatch — fusing it into layer0 was
// measured SLOWER twice (R4: +15us, R7: +5us; replicated per-block head
// beats the boundary saving).
// ---------------------------------------------------------------------------
__global__ void encode_kernel(const float* __restrict__ x, u64* __restrict__ actp0,
                              float* __restrict__ out, int out_n) {
    int idx = blockIdx.x * blockDim.x + threadIdx.x;   // 0..2047
    if (blockIdx.x == 0)
        for (int i = threadIdx.x; i < out_n; i += 256) out[i] = 0.0f;
    if (idx >= 32 * 64) return;
    int wword = idx >> 6;        // 0..31
    int b = idx & 63;
    int c = wword >> 2, j = wword & 3;
    // identical fp32 math to ref: thr = (t+1)/(NBITS+1), t = 4m+j
    float thr0 = (4 * 0 + j + 1.0f) / (NBITS + 1.0f);
    float thr1 = (4 * 1 + j + 1.0f) / (NBITS + 1.0f);
    float thr2 = (4 * 2 + j + 1.0f) / (NBITS + 1.0f);
    float thr3 = (4 * 3 + j + 1.0f) / (NBITS + 1.0f);
    const float* xb = x + b * NFEAT + c * 16;
    u64 word = 0;
    #pragma unroll
    for (int k = 0; k < 16; k++) {
        float xv = xb[k];
        word |= (u64)(xv >= thr0) << (4 * k + 0);
        word |= (u64)(xv >= thr1) << (4 * k + 1);
        word |= (u64)(xv >= thr2) << (4 * k + 2);
        word |= (u64)(xv >= thr3) << (4 * k + 3);
    }
    actp0[wword * 64 + b] = word;
}

// ---------------------------------------------------------------------------
// 64x64 bit-matrix transpose across the 64 lanes (6 butterfly stages).
// In: lane l holds row l (bit b = M[l][b]). Out: lane l holds column l.
// ---------------------------------------------------------------------------
__device__ __forceinline__ u64 bfly_stage(u64 x, int lane, int d, u64 Md) {
    u64 p = __shfl_xor(x, d);
    return (lane & d) ? ((x & Md) | ((p >> d) & ~Md))
                      : ((x & ~Md) | ((p << d) & Md));
}

__device__ __forceinline__ u64 transpose64(u64 x, int lane) {
    x = bfly_stage(x, lane, 32, 0xFFFFFFFF00000000ULL);
    x = bfly_stage(x, lane, 16, 0xFFFF0000FFFF0000ULL);
    x = bfly_stage(x, lane,  8, 0xFF00FF00FF00FF00ULL);
    x = bfly_stage(x, lane,  4, 0xF0F0F0F0F0F0F0F0ULL);
    x = bfly_stage(x, lane,  2, 0xCCCCCCCCCCCCCCCCULL);
    x = bfly_stage(x, lane,  1, 0xAAAAAAAAAAAAAAAAULL);
    return x;
}

// ---------------------------------------------------------------------------
// Layer: wave = ONE (h,s) row. 8192 waves = 1024 blocks x 512 thr = exactly
// 4 blocks/CU x 8 waves = 32 waves/CU (launch_bounds(512,8), VGPR <= 64).
// Lane = batch: act words from LDS, wave-uniform sign masks via ballot.
// Segment pair (rows 2h, 2h+1 = warps 2k, 2k+1) combines through LDS.
//  - FROM_FIRED: staging = in-block 64x64 butterfly transpose of prev
//    fired[] (64 (c,j) pairs, 8 per warp), hidden under peeled NT loads.
// ---------------------------------------------------------------------------
template <int P, bool FROM_FIRED>
__global__ __launch_bounds__(512, 8) void layer_kernel(
    const float* __restrict__ W, const u64* __restrict__ actin,
    u64* __restrict__ fired_out)
{
    constexpr int NC = P / 256;              // chunks per row
    constexpr int NW = P / 64;               // act words
    __shared__ __align__(16) u64 lds[NW * 64];   // 16 KB (P=2048) / 32 KB (4096)
    __shared__ u64 bal[8];
    int tid = threadIdx.x;
    int lane = tid & 63;
    int warp = tid >> 6;                     // 0..7
    int row = blockIdx.x * 8 + warp;         // (h,s) id, 0..8191
    const f32x4* wr = (const f32x4*)(W + (size_t)row * P) + lane;

    // peel: first 4 chunks in flight during staging
    f32x4 pw[4];
    #pragma unroll
    for (int c = 0; c < 4; c++) pw[c] = __builtin_nontemporal_load(wr + c * 64);

    if constexpr (FROM_FIRED) {
        // 64 (c,j) pairs; warp takes idx = warp*8 + k:
        // word (c,j) bit i = fired[c*256 + 4i + j] bit b  (proven in R2)
        #pragma unroll
        for (int k = 0; k < 8; k++) {
            int idx = warp * 8 + k;
            u64 xw = actin[(idx >> 2) * 256 + 4 * lane + (idx & 3)];
            xw = transpose64(xw, lane);
            lds[idx * 64 + lane] = xw;
        }
    } else {
        const ulonglong2* src = (const ulonglong2*)actin;
        ulonglong2* dst = (ulonglong2*)lds;
        for (int i = tid; i < NW * 32; i += 512) dst[i] = src[i];
    }
    __syncthreads();

    unsigned zp = 0, zn = 0;
    auto body = [&](int c, f32x4 a) {
        const u64* p = lds + c * 256 + lane;
        u64 A0 = p[0], A1 = p[64], A2 = p[128], A3 = p[192];
        u64 m;
        m = __ballot(a.x > 0.0f); zp += __builtin_popcountll(A0 & m);
        m = __ballot(a.x < 0.0f); zn += __builtin_popcountll(A0 & m);
        m = __ballot(a.y > 0.0f); zp += __builtin_popcountll(A1 & m);
        m = __ballot(a.y < 0.0f); zn += __builtin_popcountll(A1 & m);
        m = __ballot(a.z > 0.0f); zp += __builtin_popcountll(A2 & m);
        m = __ballot(a.z < 0.0f); zn += __builtin_popcountll(A2 & m);
        m = __ballot(a.w > 0.0f); zp += __builtin_popcountll(A3 & m);
        m = __ballot(a.w < 0.0f); zn += __builtin_popcountll(A3 & m);
    };
    #pragma unroll
    for (int c = 0; c < 4; c++) body(c, pw[c]);
    #pragma unroll 4
    for (int c = 4; c < NC; c++)
        body(c, __builtin_nontemporal_load(wr + c * 64));

    int z = (int)zp - (int)zn;
    u64 bz = __ballot(z >= THETA);
    if (lane == 0) bal[warp] = bz;
    __syncthreads();
    // h = blockIdx*4 + t sources rows 8*blockIdx + 2t (s=0) and +1 (s=1)
    if (tid < 4) fired_out[blockIdx.x * 4 + tid] = bal[2 * tid] | bal[2 * tid + 1];
}

// ---------------------------------------------------------------------------
// Output: out[b,c] = sum_l sum_h fired_l[b,h] * outW[l,h,c]; lane = batch.
// Block-uniform (l,c); 4 wave-partials reduce in LDS -> 1 atomic per
// (block, lane). grid: 480 blocks x 256 thr (3 x 10 x 64 chunks of 64 h).
// ---------------------------------------------------------------------------
__global__ void output_kernel(const float* __restrict__ outW,
                              const u64* __restrict__ fired,
                              float* __restrict__ out) {
    __shared__ float red[4][64];
    int tid = threadIdx.x;
    int lane = tid & 63;
    int warp = tid >> 6;
    int wid = blockIdx.x * 4 + warp;   // 0..1919
    int l = wid / (NCLS * 64);
    int rem = wid % (NCLS * 64);
    int c = rem / 64;
    int chunk = rem % 64;
    const u64* fl = fired + l * H_SZ;
    int h0 = chunk * 64;
    float acc = 0.0f;
    #pragma unroll 8
    for (int h = h0; h < h0 + 64; h++) {
        float wv = outW[((size_t)(l * H_SZ + h)) * NCLS + c];
        if ((fl[h] >> lane) & 1ULL) acc += wv;
    }
    red[warp][lane] = acc;
    __syncthreads();
    if (warp == 0) {
        float s = red[0][lane] + red[1][lane] + red[2][lane] + red[3][lane];
        atomicAdd(&out[lane * NCLS + c], s);
    }
}

// ---------------------------------------------------------------------------
extern "C" void kernel_launch(void* const* d_in, const int* in_sizes, int n_in,
                              void* d_out, int out_size, void* d_ws, size_t ws_size,
                              hipStream_t stream) {
    const float* x    = (const float*)d_in[0];
    const float* W0   = (const float*)d_in[1];
    const float* W1   = (const float*)d_in[2];
    const float* W2   = (const float*)d_in[3];
    const float* outW = (const float*)d_in[4];
    float* out = (float*)d_out;

    char* ws = (char*)d_ws;
    u64* fired = (u64*)(ws);                 // 3*4096 u64 = 96 KB
    u64* actp0 = (u64*)(ws + 98304);         // 2048 u64  = 16 KB

    encode_kernel<<<8, 256, 0, stream>>>(x, actp0, out, out_size);

    layer_kernel<2048, false><<<1024, 512, 0, stream>>>(W0, actp0, fired);
    layer_kernel<4096, true ><<<1024, 512, 0, stream>>>(W1, fired, fired + H_SZ);
    layer_kernel<4096, true ><<<1024, 512, 0, stream>>>(W2, fired + H_SZ, fired + 2 * H_SZ);

    output_kernel<<<480, 256, 0, stream>>>(outW, fired, out);
}